// Round 4
// baseline (514.052 us; speedup 1.0000x reference)
//
#include <hip/hip_runtime.h>

// GAT as flash-attention, round 4: barrier-free phase 2.
//  - K/V MFMA fragments loaded DIRECTLY from global (h16/hT16 are L2/L3-hot,
//    2 MB/batch): no LDS staging, no __syncthreads, waves fully independent.
//  - adj (the 268 MB HBM stream) prefetched one 64-j super-tile ahead
//    (~4 iterations of compute slack vs ~900 cyc HBM latency).
//  - fixed-scale softmax (exp2, no running max); j-split x4; fp16 pipeline.
//  - phase1: W kept in natural [k][f] LDS layout -> broadcast/2-way reads only.

typedef __attribute__((ext_vector_type(4))) float f32x4;
typedef __attribute__((ext_vector_type(4))) _Float16 h16x4;
typedef __attribute__((ext_vector_type(8))) _Float16 h16x8;
typedef __attribute__((ext_vector_type(2))) __fp16 fp16x2;

#define L2E 1.4426950408889634f

// ---------------- phase 1: h = x@W (fp32), scaled biases, fp16 packs --------
// 512 blocks x 256 thr; block = 32 rows x 64 f; thread tile = 2 rows x 4 f.
__global__ __launch_bounds__(256) void gat_phase1(
    const float* __restrict__ x,        // [4][4096][128]
    const float* __restrict__ W,        // [128][64]
    const float* __restrict__ a,        // [192]
    _Float16* __restrict__ h16,         // [4][4096][64]
    _Float16* __restrict__ hT16,        // [4][64][4096]
    _Float16* __restrict__ q16,         // [4][4096][64]  (pre-scaled by log2e)
    float* __restrict__ sS,             // [4][4096]      (pre-scaled by log2e)
    float* __restrict__ sN)             // [4][4096]      (pre-scaled by log2e)
{
  __shared__ float xs[32 * 132];        // x tile [row][k], stride 132
  __shared__ float ws[128 * 64];        // W natural [k][f] (32 KB)
  const int tid = threadIdx.x;
  const int bx  = blockIdx.x;
  const int b   = bx >> 7;
  const int n0  = (bx & 127) << 5;
  const float* xb = x + ((size_t)b * 4096 + n0) * 128;

#pragma unroll
  for (int p = 0; p < 4; ++p) {
    int idx = tid + p * 256;
    int row = idx >> 5, c4 = idx & 31;
    float4 v = ((const float4*)(xb + row * 128))[c4];
    *(float4*)&xs[row * 132 + c4 * 4] = v;
  }
#pragma unroll
  for (int p = 0; p < 8; ++p) {
    int idx = tid + p * 256;
    ((float4*)ws)[idx] = ((const float4*)W)[idx];
  }
  __syncthreads();

  const int tx = tid & 15;   // f = 4*tx + fi
  const int ty = tid >> 4;   // n = n0 + 2*ty + ri
  f32x4 acc0 = (f32x4){0.f, 0.f, 0.f, 0.f};
  f32x4 acc1 = (f32x4){0.f, 0.f, 0.f, 0.f};

#pragma unroll 8
  for (int k = 0; k < 128; k += 4) {
    f32x4 x0 = *(const f32x4*)&xs[(2 * ty) * 132 + k];       // broadcast
    f32x4 x1 = *(const f32x4*)&xs[(2 * ty + 1) * 132 + k];
    f32x4 w0 = *(const f32x4*)&ws[(k + 0) * 64 + 4 * tx];    // 2-way, free
    f32x4 w1 = *(const f32x4*)&ws[(k + 1) * 64 + 4 * tx];
    f32x4 w2 = *(const f32x4*)&ws[(k + 2) * 64 + 4 * tx];
    f32x4 w3 = *(const f32x4*)&ws[(k + 3) * 64 + 4 * tx];
    acc0 += x0.x * w0 + x0.y * w1 + x0.z * w2 + x0.w * w3;
    acc1 += x1.x * w0 + x1.y * w1 + x1.z * w2 + x1.w * w3;
  }
  float acc[2][4] = {{acc0.x, acc0.y, acc0.z, acc0.w},
                     {acc1.x, acc1.y, acc1.z, acc1.w}};

  float a1r[4], a2r[4], a3r[4];
#pragma unroll
  for (int f = 0; f < 4; ++f) {
    a1r[f] = a[4 * tx + f] * L2E;
    a2r[f] = a[64 + 4 * tx + f] * L2E;
    a3r[f] = a[128 + 4 * tx + f] * L2E;
  }
  const size_t bN = (size_t)b * 4096;
#pragma unroll
  for (int r = 0; r < 2; ++r) {
    float p1 = 0.f, p2 = 0.f;
#pragma unroll
    for (int f = 0; f < 4; ++f) { p1 += acc[r][f] * a1r[f]; p2 += acc[r][f] * a2r[f]; }
#pragma unroll
    for (int m = 1; m < 16; m <<= 1) {
      p1 += __shfl_xor(p1, m, 64);
      p2 += __shfl_xor(p2, m, 64);
    }
    if (tx == 0) {
      int n = n0 + 2 * ty + r;
      sS[bN + n] = p1;
      sN[bN + n] = p2;
    }
  }
#pragma unroll
  for (int r = 0; r < 2; ++r) {
    int n = n0 + 2 * ty + r;
    h16x4 hv, qv;
#pragma unroll
    for (int f = 0; f < 4; ++f) {
      hv[f] = (_Float16)acc[r][f];
      qv[f] = (_Float16)(acc[r][f] * a3r[f]);
    }
    *(h16x4*)&h16[(bN + n) * 64 + 4 * tx] = hv;
    *(h16x4*)&q16[(bN + n) * 64 + 4 * tx] = qv;
  }
  __syncthreads();                       // xs reads done; reuse as hT staging
  _Float16* hTs = (_Float16*)xs;         // [64][40] halves (5.1 KB)
#pragma unroll
  for (int f = 0; f < 4; ++f)
#pragma unroll
    for (int r = 0; r < 2; ++r)
      hTs[(4 * tx + f) * 40 + 2 * ty + r] = (_Float16)acc[r][f];
  __syncthreads();
  {
    int f = tid >> 2, part = tid & 3;    // 16B per thread, 64B per f-row
    uint4 v = *(uint4*)&hTs[f * 40 + 8 * part];
    *(uint4*)&hT16[((size_t)b * 64 + f) * 4096 + n0 + 8 * part] = v;
  }
}

// ---------------- phase 2: masked softmax-attention partials ----------------
// 1024 blocks (b,split,itile) x 256 thr = 4 INDEPENDENT waves (no LDS, no
// barriers). Wave w owns 16 Q-rows; 64 iterations of 16 j's each.
// MFMA layouts: 16x16x32 A[m=lane&15][k=qd*8+j], B[k=qd*8+j][n=lane&15],
//               16x16x16 B[k=qd*4+r][n=lane&15], C/D row=4*qd+reg, col=lane&15.
__global__ __launch_bounds__(256, 4) void gat_phase2(
    const _Float16* __restrict__ h16,
    const _Float16* __restrict__ hT16,
    const _Float16* __restrict__ q16,
    const float* __restrict__ sS,
    const float* __restrict__ sN,
    const int* __restrict__ adj,
    float* __restrict__ Opart,          // [4][16384][64]
    float* __restrict__ lpart)          // [4][16384]
{
  const int tid = threadIdx.x;
  const int w = tid >> 6, lane = tid & 63;
  const int qd = lane >> 4, c = lane & 15;
  const int bx = blockIdx.x;
  const int b = bx & 3;
  const int split = (bx >> 2) & 3;
  const int it = bx >> 4;
  const int i0 = it * 64 + w * 16;
  const int jq0 = split * 1024;
  const size_t bN = (size_t)b * 4096;

  // Q fragment: B-operand of S^T (Q^T[f][i]), lane holds Q[i=i0+c][f-slice]
  const _Float16* qrow = q16 + (bN + i0 + c) * 64;
  h16x8 Qf0 = *(const h16x8*)(qrow + qd * 8);
  h16x8 Qf1 = *(const h16x8*)(qrow + 32 + qd * 8);
  const float ss = sS[bN + i0 + c];

  // direct-global fragment bases
  const _Float16* kbase = h16 + (bN + jq0 + c) * 64 + qd * 8;           // +j*64
  const _Float16* vbase = hT16 + ((size_t)b * 64 + c) * 4096 + jq0 + 4 * qd;
  const int* abase = adj + (bN + i0 + c) * 4096 + jq0 + 4 * qd;
  const float* snb = sN + bN + jq0 + 4 * qd;

  f32x4 O[4];
#pragma unroll
  for (int ft = 0; ft < 4; ++ft) O[ft] = (f32x4){0.f, 0.f, 0.f, 0.f};
  float lsum = 0.f;

  // adj prefetch: one 64-j super-tile (4 iterations) ahead
  uint4 av[4];
#pragma unroll
  for (int ct = 0; ct < 4; ++ct) av[ct] = *(const uint4*)(abase + 16 * ct);

  for (int t = 0; t < 16; ++t) {
    const int j0 = t * 64;
    uint4 avn[4] = {av[0], av[1], av[2], av[3]};
    if (t < 15) {
#pragma unroll
      for (int ct = 0; ct < 4; ++ct)
        avn[ct] = *(const uint4*)(abase + j0 + 64 + 16 * ct);
    }

#pragma unroll
    for (int ct = 0; ct < 4; ++ct) {
      const int j = j0 + 16 * ct;
      // K fragment (A-op of S^T): rows j..j+15, f split in two 32-chunks
      h16x8 Kf0 = *(const h16x8*)(kbase + j * 64);
      h16x8 Kf1 = *(const h16x8*)(kbase + j * 64 + 32);
      // V^T fragments (B-op of PV): rows f=16ft+c, cols j+4qd..+3
      h16x4 Vf0 = *(const h16x4*)(vbase + (size_t)0 * 65536 + j);
      h16x4 Vf1 = *(const h16x4*)(vbase + (size_t)1 * 65536 + j);
      h16x4 Vf2 = *(const h16x4*)(vbase + (size_t)2 * 65536 + j);
      h16x4 Vf3 = *(const h16x4*)(vbase + (size_t)3 * 65536 + j);
      f32x4 snv = *(const f32x4*)(snb + j);

      f32x4 Sv = (f32x4){0.f, 0.f, 0.f, 0.f};
      Sv = __builtin_amdgcn_mfma_f32_16x16x32_f16(Kf0, Qf0, Sv, 0, 0, 0);
      Sv = __builtin_amdgcn_mfma_f32_16x16x32_f16(Kf1, Qf1, Sv, 0, 0, 0);

      f32x4 ev = Sv + snv + ss;                    // e * log2e
      f32x4 tv = __builtin_elementwise_max(ev, ev * 0.2f);  // leakyrelu
      float p0 = __builtin_amdgcn_exp2f(tv.x);
      float p1 = __builtin_amdgcn_exp2f(tv.y);
      float p2 = __builtin_amdgcn_exp2f(tv.z);
      float p3 = __builtin_amdgcn_exp2f(tv.w);
      p0 = av[ct].x ? p0 : 0.f;
      p1 = av[ct].y ? p1 : 0.f;
      p2 = av[ct].z ? p2 : 0.f;
      p3 = av[ct].w ? p3 : 0.f;
      lsum += (p0 + p1) + (p2 + p3);
      fp16x2 plo = __builtin_amdgcn_cvt_pkrtz(p0, p1);
      fp16x2 phi = __builtin_amdgcn_cvt_pkrtz(p2, p3);
      h16x4 Pf = (h16x4){(_Float16)plo.x, (_Float16)plo.y,
                         (_Float16)phi.x, (_Float16)phi.y};  // P^T[j+4qd+r][i0+c]

      // O^T[f][i] += V^T[f][j] * P^T[j][i]
      O[0] = __builtin_amdgcn_mfma_f32_16x16x16f16(Vf0, Pf, O[0], 0, 0, 0);
      O[1] = __builtin_amdgcn_mfma_f32_16x16x16f16(Vf1, Pf, O[1], 0, 0, 0);
      O[2] = __builtin_amdgcn_mfma_f32_16x16x16f16(Vf2, Pf, O[2], 0, 0, 0);
      O[3] = __builtin_amdgcn_mfma_f32_16x16x16f16(Vf3, Pf, O[3], 0, 0, 0);
    }
#pragma unroll
    for (int ct = 0; ct < 4; ++ct) av[ct] = avn[ct];
  }

  // l: sum over qd groups (full j-quarter per row i=i0+c)
  lsum += __shfl_xor(lsum, 16, 64);
  lsum += __shfl_xor(lsum, 32, 64);

  // lane c owns output row i0+c: O^T col=c, rows f=16ft+4qd+r (contig in r)
  float* orow = Opart + ((size_t)split * 16384 + bN + i0 + c) * 64;
#pragma unroll
  for (int ft = 0; ft < 4; ++ft)
    *(f32x4*)(orow + 16 * ft + 4 * qd) = O[ft];
  if (lane < 16) lpart[split * 16384 + bN + i0 + c] = lsum;
}

// ---------------- phase 3: combine splits + normalize + ELU ----------------
__global__ __launch_bounds__(256) void gat_combine(
    const float* __restrict__ Opart, const float* __restrict__ lpart,
    float* __restrict__ out)
{
  const int tid = threadIdx.x;
  const size_t row = (size_t)blockIdx.x * 16 + (tid >> 4);
  const int f4 = (tid & 15) * 4;
  const size_t R = 16384;
  float l = lpart[row] + lpart[R + row] + lpart[2 * R + row] + lpart[3 * R + row];
  f32x4 o = *(const f32x4*)&Opart[row * 64 + f4];
  o += *(const f32x4*)&Opart[(R + row) * 64 + f4];
  o += *(const f32x4*)&Opart[(2 * R + row) * 64 + f4];
  o += *(const f32x4*)&Opart[(3 * R + row) * 64 + f4];
  float inv = 1.0f / l;
  float4 res;
  float v;
  v = o.x * inv; res.x = v > 0.f ? v : __expf(v) - 1.f;
  v = o.y * inv; res.y = v > 0.f ? v : __expf(v) - 1.f;
  v = o.z * inv; res.z = v > 0.f ? v : __expf(v) - 1.f;
  v = o.w * inv; res.w = v > 0.f ? v : __expf(v) - 1.f;
  *(float4*)&out[row * 64 + f4] = res;
}

extern "C" void kernel_launch(void* const* d_in, const int* in_sizes, int n_in,
                              void* d_out, int out_size, void* d_ws, size_t ws_size,
                              hipStream_t stream) {
  const float* x  = (const float*)d_in[0];
  const int* adj  = (const int*)d_in[1];
  const float* W  = (const float*)d_in[2];
  const float* a  = (const float*)d_in[3];
  float* out = (float*)d_out;

  char* ws = (char*)d_ws;
  _Float16* h16  = (_Float16*)(ws);                      // 2 MB
  _Float16* hT16 = (_Float16*)(ws + (2u << 20));         // 2 MB
  _Float16* q16  = (_Float16*)(ws + (4u << 20));         // 2 MB
  float* sS = (float*)(ws + (6u << 20));                 // 64 KB
  float* sN = (float*)(ws + (6u << 20) + (64u << 10));   // 64 KB
  float* Opart = (float*)(ws + (6u << 20) + (128u << 10));          // 16.78 MB
  float* lpart = (float*)(ws + (6u << 20) + (128u << 10) + (16u << 20)); // 256 KB

  gat_phase1<<<512, 256, 0, stream>>>(x, W, a, h16, hT16, q16, sS, sN);
  gat_phase2<<<1024, 256, 0, stream>>>(h16, hT16, q16, sS, sN, adj, Opart, lpart);
  gat_combine<<<1024, 256, 0, stream>>>(Opart, lpart, out);
}

// Round 5
// 448.266 us; speedup vs baseline: 1.1468x; 1.1468x over previous
//
#include <hip/hip_runtime.h>

// GAT as flash-attention, round 5:
//  - adj decoupled: gat_mask streams adj once at HBM roofline (268 MB) into a
//    packed 64-bit-per-64j bitmask (8.4 MB, L2/L3-hot). Phase 2 has NO HBM
//    dependency -> no 900-cyc vmcnt serialization (the round-4 killer).
//  - phase2: K/V staged via double-buffered LDS (1 barrier/tile), fragments
//    read from LDS (lgkmcnt domain), masks via 8 B load + shifts.
//  - fixed-scale softmax (exp2, no running max); S^T formulation; j-split x4.

typedef __attribute__((ext_vector_type(4))) float f32x4;
typedef __attribute__((ext_vector_type(4))) _Float16 h16x4;
typedef __attribute__((ext_vector_type(8))) _Float16 h16x8;
typedef __attribute__((ext_vector_type(2))) __fp16 fp16x2;

#define L2E 1.4426950408889634f

// ---------------- phase 0: adj -> bitmask (pure HBM stream) ----------------
// 4096 blocks x 256 thr; wave w handles row bx*4+w; ballot packs 64 j's/iter.
__global__ __launch_bounds__(256) void gat_mask(
    const int* __restrict__ adj,                 // [4][4096][4096]
    unsigned long long* __restrict__ mask)       // [4][4096][64]
{
  const int tid = threadIdx.x;
  const int w = tid >> 6, lane = tid & 63;
  const size_t row = (size_t)blockIdx.x * 4 + w;
  const int* ap = adj + row * 4096 + lane;
  unsigned long long* mp = mask + row * 64;
#pragma unroll 4
  for (int s = 0; s < 64; ++s) {
    int v = ap[s * 64];
    unsigned long long m = __ballot(v > 0);      // bit l = adj[row][s*64+l]>0
    if (lane == 0) mp[s] = m;
  }
}

// ---------------- phase 1: h = x@W (fp32), scaled biases, fp16 packs --------
__global__ __launch_bounds__(256) void gat_phase1(
    const float* __restrict__ x,        // [4][4096][128]
    const float* __restrict__ W,        // [128][64]
    const float* __restrict__ a,        // [192]
    _Float16* __restrict__ h16,         // [4][4096][64]
    _Float16* __restrict__ hT16,        // [4][64][4096]
    _Float16* __restrict__ q16,         // [4][4096][64]  (pre-scaled by log2e)
    float* __restrict__ sS,             // [4][4096]      (pre-scaled by log2e)
    float* __restrict__ sN)             // [4][4096]      (pre-scaled by log2e)
{
  __shared__ float xs[32 * 132];        // x tile [row][k], stride 132
  __shared__ float ws[128 * 64];        // W natural [k][f] (broadcast/2-way)
  const int tid = threadIdx.x;
  const int bx  = blockIdx.x;
  const int b   = bx >> 7;
  const int n0  = (bx & 127) << 5;
  const float* xb = x + ((size_t)b * 4096 + n0) * 128;

#pragma unroll
  for (int p = 0; p < 4; ++p) {
    int idx = tid + p * 256;
    int row = idx >> 5, c4 = idx & 31;
    float4 v = ((const float4*)(xb + row * 128))[c4];
    *(float4*)&xs[row * 132 + c4 * 4] = v;
  }
#pragma unroll
  for (int p = 0; p < 8; ++p) {
    int idx = tid + p * 256;
    ((float4*)ws)[idx] = ((const float4*)W)[idx];
  }
  __syncthreads();

  const int tx = tid & 15;   // f = 4*tx + fi
  const int ty = tid >> 4;   // n = n0 + 2*ty + ri
  f32x4 acc0 = (f32x4){0.f, 0.f, 0.f, 0.f};
  f32x4 acc1 = (f32x4){0.f, 0.f, 0.f, 0.f};

#pragma unroll 8
  for (int k = 0; k < 128; k += 4) {
    f32x4 x0 = *(const f32x4*)&xs[(2 * ty) * 132 + k];
    f32x4 x1 = *(const f32x4*)&xs[(2 * ty + 1) * 132 + k];
    f32x4 w0 = *(const f32x4*)&ws[(k + 0) * 64 + 4 * tx];
    f32x4 w1 = *(const f32x4*)&ws[(k + 1) * 64 + 4 * tx];
    f32x4 w2 = *(const f32x4*)&ws[(k + 2) * 64 + 4 * tx];
    f32x4 w3 = *(const f32x4*)&ws[(k + 3) * 64 + 4 * tx];
    acc0 += x0.x * w0 + x0.y * w1 + x0.z * w2 + x0.w * w3;
    acc1 += x1.x * w0 + x1.y * w1 + x1.z * w2 + x1.w * w3;
  }
  float acc[2][4] = {{acc0.x, acc0.y, acc0.z, acc0.w},
                     {acc1.x, acc1.y, acc1.z, acc1.w}};

  float a1r[4], a2r[4], a3r[4];
#pragma unroll
  for (int f = 0; f < 4; ++f) {
    a1r[f] = a[4 * tx + f] * L2E;
    a2r[f] = a[64 + 4 * tx + f] * L2E;
    a3r[f] = a[128 + 4 * tx + f] * L2E;
  }
  const size_t bN = (size_t)b * 4096;
#pragma unroll
  for (int r = 0; r < 2; ++r) {
    float p1 = 0.f, p2 = 0.f;
#pragma unroll
    for (int f = 0; f < 4; ++f) { p1 += acc[r][f] * a1r[f]; p2 += acc[r][f] * a2r[f]; }
#pragma unroll
    for (int m = 1; m < 16; m <<= 1) {
      p1 += __shfl_xor(p1, m, 64);
      p2 += __shfl_xor(p2, m, 64);
    }
    if (tx == 0) {
      int n = n0 + 2 * ty + r;
      sS[bN + n] = p1;
      sN[bN + n] = p2;
    }
  }
#pragma unroll
  for (int r = 0; r < 2; ++r) {
    int n = n0 + 2 * ty + r;
    h16x4 hv, qv;
#pragma unroll
    for (int f = 0; f < 4; ++f) {
      hv[f] = (_Float16)acc[r][f];
      qv[f] = (_Float16)(acc[r][f] * a3r[f]);
    }
    *(h16x4*)&h16[(bN + n) * 64 + 4 * tx] = hv;
    *(h16x4*)&q16[(bN + n) * 64 + 4 * tx] = qv;
  }
  __syncthreads();                       // xs reads done; reuse as hT staging
  _Float16* hTs = (_Float16*)xs;         // [64][40] halves
#pragma unroll
  for (int f = 0; f < 4; ++f)
#pragma unroll
    for (int r = 0; r < 2; ++r)
      hTs[(4 * tx + f) * 40 + 2 * ty + r] = (_Float16)acc[r][f];
  __syncthreads();
  {
    int f = tid >> 2, part = tid & 3;
    uint4 v = *(uint4*)&hTs[f * 40 + 8 * part];
    *(uint4*)&hT16[((size_t)b * 64 + f) * 4096 + n0 + 8 * part] = v;
  }
}

// ---------------- phase 2: masked softmax-attention partials ----------------
// 1024 blocks (b,split,itile) x 256 thr (4 waves x 16 rows). j-quarter = 1024.
// Double-buffered LDS staging, ONE barrier per 64-j tile. No HBM reads.
// MFMA layouts: 16x16x32 A[m=lane&15][k=qd*8+j], B[k=qd*8+j][n=lane&15],
//               16x16x16 B[k=qd*4+r][n=lane&15], C/D row=4*qd+reg, col=lane&15.
__global__ __launch_bounds__(256, 4) void gat_phase2(
    const _Float16* __restrict__ h16,
    const _Float16* __restrict__ hT16,
    const _Float16* __restrict__ q16,
    const float* __restrict__ sS,
    const float* __restrict__ sN,
    const unsigned long long* __restrict__ mask,  // [4][4096][64]
    float* __restrict__ Opart,          // [4][16384][64]
    float* __restrict__ lpart)          // [4][16384]
{
  __shared__ _Float16 Kb[2][64 * 72];   // K rows [j][f], stride 72
  __shared__ _Float16 Tb[2][64 * 72];   // V^T rows [f][j]

  const int tid = threadIdx.x;
  const int w = tid >> 6, lane = tid & 63;
  const int qd = lane >> 4, c = lane & 15;
  const int bx = blockIdx.x;
  const int b = bx & 3;
  const int split = (bx >> 2) & 3;
  const int it = bx >> 4;
  const int i0 = it * 64 + w * 16;
  const int jq0 = split * 1024;
  const size_t bN = (size_t)b * 4096;

  // Q fragment: B-operand of S^T (Q^T[f][i]), lane holds Q[i=i0+c][f-slice]
  const _Float16* qrow = q16 + (bN + i0 + c) * 64;
  h16x8 Qf0 = *(const h16x8*)(qrow + qd * 8);
  h16x8 Qf1 = *(const h16x8*)(qrow + 32 + qd * 8);
  const float ss = sS[bN + i0 + c];
  const int sh0 = 4 * qd;

  const unsigned long long* mrow = mask + (bN + i0 + c) * 64 + (jq0 >> 6);
  const float* snb = sN + bN + jq0 + 4 * qd;

  // staging addressing (coalesced uint4; whole block shares each tile)
  const int srow = tid >> 3, sc8 = (tid & 7) * 8;
  const _Float16* hsrc = h16 + (bN + jq0 + srow) * 64 + sc8;
  const _Float16* tsrc = hT16 + ((size_t)b * 64 + srow) * 4096 + jq0 + sc8;

  f32x4 O[4];
#pragma unroll
  for (int ft = 0; ft < 4; ++ft) O[ft] = (f32x4){0.f, 0.f, 0.f, 0.f};
  float lsum = 0.f;

  // tile 0 into buffer 0
  {
    uint4 k0 = *(const uint4*)hsrc, k1 = *(const uint4*)(hsrc + 32 * 64);
    uint4 t0 = *(const uint4*)tsrc, t1 = *(const uint4*)(tsrc + 32 * 4096);
    *(uint4*)&Kb[0][srow * 72 + sc8] = k0;
    *(uint4*)&Kb[0][(srow + 32) * 72 + sc8] = k1;
    *(uint4*)&Tb[0][srow * 72 + sc8] = t0;
    *(uint4*)&Tb[0][(srow + 32) * 72 + sc8] = t1;
  }

  for (int t = 0; t < 16; ++t) {
    const int bi = t & 1;
    unsigned long long m64 = mrow[t];               // issued before prefetch
    uint4 kr0, kr1, tr0, tr1;
    if (t < 15) {                                   // prefetch next tile (L2)
      const _Float16* hs = hsrc + (t + 1) * 64 * 64;
      const _Float16* ts = tsrc + (t + 1) * 64;
      kr0 = *(const uint4*)hs; kr1 = *(const uint4*)(hs + 32 * 64);
      tr0 = *(const uint4*)ts; tr1 = *(const uint4*)(ts + 32 * 4096);
    }
    __syncthreads();                                // buf[bi] visible

    const _Float16* Kc = &Kb[bi][0];
    const _Float16* Tc = &Tb[bi][0];
    const int j0 = t * 64;
#pragma unroll
    for (int ct = 0; ct < 4; ++ct) {
      h16x8 Kf0 = *(const h16x8*)&Kc[(16 * ct + c) * 72 + qd * 8];
      h16x8 Kf1 = *(const h16x8*)&Kc[(16 * ct + c) * 72 + 32 + qd * 8];
      f32x4 Sv = (f32x4){0.f, 0.f, 0.f, 0.f};
      Sv = __builtin_amdgcn_mfma_f32_16x16x32_f16(Kf0, Qf0, Sv, 0, 0, 0);
      Sv = __builtin_amdgcn_mfma_f32_16x16x32_f16(Kf1, Qf1, Sv, 0, 0, 0);

      f32x4 snv = *(const f32x4*)(snb + j0 + 16 * ct);
      f32x4 ev = Sv + snv + ss;                     // e * log2e
      f32x4 tv = __builtin_elementwise_max(ev, ev * 0.2f);  // leakyrelu
      unsigned int bits = (unsigned int)(m64 >> (sh0 + 16 * ct));
      float p0 = __builtin_amdgcn_exp2f(tv.x);
      float p1 = __builtin_amdgcn_exp2f(tv.y);
      float p2 = __builtin_amdgcn_exp2f(tv.z);
      float p3 = __builtin_amdgcn_exp2f(tv.w);
      p0 = (bits & 1u) ? p0 : 0.f;
      p1 = (bits & 2u) ? p1 : 0.f;
      p2 = (bits & 4u) ? p2 : 0.f;
      p3 = (bits & 8u) ? p3 : 0.f;
      lsum += (p0 + p1) + (p2 + p3);
      fp16x2 plo = __builtin_amdgcn_cvt_pkrtz(p0, p1);
      fp16x2 phi = __builtin_amdgcn_cvt_pkrtz(p2, p3);
      h16x4 Pf = (h16x4){(_Float16)plo.x, (_Float16)plo.y,
                         (_Float16)phi.x, (_Float16)phi.y};  // P^T[j][i=c]

      // O^T[f][i] += V^T[f][j] * P^T[j][i]
#pragma unroll
      for (int ft = 0; ft < 4; ++ft) {
        h16x4 Vf = *(const h16x4*)&Tc[(16 * ft + c) * 72 + 16 * ct + 4 * qd];
        O[ft] = __builtin_amdgcn_mfma_f32_16x16x16f16(Vf, Pf, O[ft], 0, 0, 0);
      }
    }

    if (t < 15) {                                   // fill the other buffer
      *(uint4*)&Kb[bi ^ 1][srow * 72 + sc8] = kr0;
      *(uint4*)&Kb[bi ^ 1][(srow + 32) * 72 + sc8] = kr1;
      *(uint4*)&Tb[bi ^ 1][srow * 72 + sc8] = tr0;
      *(uint4*)&Tb[bi ^ 1][(srow + 32) * 72 + sc8] = tr1;
    }
  }

  // l: sum over qd groups (full j-quarter per row i=i0+c)
  lsum += __shfl_xor(lsum, 16, 64);
  lsum += __shfl_xor(lsum, 32, 64);

  float* orow = Opart + ((size_t)split * 16384 + bN + i0 + c) * 64;
#pragma unroll
  for (int ft = 0; ft < 4; ++ft)
    *(f32x4*)(orow + 16 * ft + 4 * qd) = O[ft];
  if (lane < 16) lpart[split * 16384 + bN + i0 + c] = lsum;
}

// ---------------- phase 3: combine splits + normalize + ELU ----------------
__global__ __launch_bounds__(256) void gat_combine(
    const float* __restrict__ Opart, const float* __restrict__ lpart,
    float* __restrict__ out)
{
  const int tid = threadIdx.x;
  const size_t row = (size_t)blockIdx.x * 16 + (tid >> 4);
  const int f4 = (tid & 15) * 4;
  const size_t R = 16384;
  float l = lpart[row] + lpart[R + row] + lpart[2 * R + row] + lpart[3 * R + row];
  f32x4 o = *(const f32x4*)&Opart[row * 64 + f4];
  o += *(const f32x4*)&Opart[(R + row) * 64 + f4];
  o += *(const f32x4*)&Opart[(2 * R + row) * 64 + f4];
  o += *(const f32x4*)&Opart[(3 * R + row) * 64 + f4];
  float inv = 1.0f / l;
  float4 res;
  float v;
  v = o.x * inv; res.x = v > 0.f ? v : __expf(v) - 1.f;
  v = o.y * inv; res.y = v > 0.f ? v : __expf(v) - 1.f;
  v = o.z * inv; res.z = v > 0.f ? v : __expf(v) - 1.f;
  v = o.w * inv; res.w = v > 0.f ? v : __expf(v) - 1.f;
  *(float4*)&out[row * 64 + f4] = res;
}

extern "C" void kernel_launch(void* const* d_in, const int* in_sizes, int n_in,
                              void* d_out, int out_size, void* d_ws, size_t ws_size,
                              hipStream_t stream) {
  const float* x  = (const float*)d_in[0];
  const int* adj  = (const int*)d_in[1];
  const float* W  = (const float*)d_in[2];
  const float* a  = (const float*)d_in[3];
  float* out = (float*)d_out;

  char* ws = (char*)d_ws;
  _Float16* h16  = (_Float16*)(ws);                      // 2 MB
  _Float16* hT16 = (_Float16*)(ws + (2u << 20));         // 2 MB
  _Float16* q16  = (_Float16*)(ws + (4u << 20));         // 2 MB
  float* sS = (float*)(ws + (6u << 20));                 // 64 KB
  float* sN = (float*)(ws + (6u << 20) + (64u << 10));   // 64 KB
  float* Opart = (float*)(ws + (6u << 20) + (128u << 10));               // 16 MB
  float* lpart = (float*)(ws + (6u << 20) + (128u << 10) + (16u << 20)); // 256 KB
  unsigned long long* mask =
      (unsigned long long*)(ws + (6u << 20) + (128u << 10) + (16u << 20) + (256u << 10)); // 8.4 MB

  gat_mask<<<4096, 256, 0, stream>>>(adj, mask);
  gat_phase1<<<512, 256, 0, stream>>>(x, W, a, h16, hT16, q16, sS, sN);
  gat_phase2<<<1024, 256, 0, stream>>>(h16, hT16, q16, sS, sN, mask, Opart, lpart);
  gat_combine<<<1024, 256, 0, stream>>>(Opart, lpart, out);
}